// Round 5
// baseline (837.416 us; speedup 1.0000x reference)
//
#include <hip/hip_runtime.h>
#include <math.h>

#define N_NODES 100000
#define N_EDGES 1600000
#define D 64
#define NBUK 391        // ceil(N_NODES/256), 256 rows per bucket

typedef unsigned int u32;

// ---------------------------------------------------------------------------
// K1: h = feat @ kern  (fp32 vector GEMM, K=64, D_OUT=64)
//     block 0 additionally zeroes the bucket counters (runs before hist in
//     stream order).
// ---------------------------------------------------------------------------
__global__ __launch_bounds__(256) void gemm_kernel(
    const float* __restrict__ feat, const float* __restrict__ kern,
    float* __restrict__ h, u32* __restrict__ bcnt)
{
    __shared__ float ks[64 * 64];
    __shared__ float fs[16 * 64];

    const int t = threadIdx.x;
    const int row0 = blockIdx.x * 16;

    if (blockIdx.x == 0)
        for (int i = t; i < NBUK; i += 256) bcnt[i] = 0u;

    {
        const float4* k4 = (const float4*)kern;
        float4* ks4 = (float4*)ks;
        #pragma unroll
        for (int i = 0; i < 4; i++) ks4[t + 256 * i] = k4[t + 256 * i];
    }
    {
        const float4* f4 = (const float4*)(feat + (size_t)row0 * D);
        ((float4*)fs)[t] = f4[t];
    }
    __syncthreads();

    const int r  = t >> 4;
    const int cg = t & 15;

    float4 acc = make_float4(0.f, 0.f, 0.f, 0.f);
    #pragma unroll
    for (int k4 = 0; k4 < 16; k4++) {
        float4 f  = ((const float4*)(fs + r * D))[k4];
        float4 k0 = ((const float4*)(ks + (4 * k4 + 0) * D))[cg];
        float4 k1 = ((const float4*)(ks + (4 * k4 + 1) * D))[cg];
        float4 k2 = ((const float4*)(ks + (4 * k4 + 2) * D))[cg];
        float4 k3 = ((const float4*)(ks + (4 * k4 + 3) * D))[cg];
        acc.x += f.x * k0.x + f.y * k1.x + f.z * k2.x + f.w * k3.x;
        acc.y += f.x * k0.y + f.y * k1.y + f.z * k2.y + f.w * k3.y;
        acc.z += f.x * k0.z + f.y * k1.z + f.z * k2.z + f.w * k3.z;
        acc.w += f.x * k0.w + f.y * k1.w + f.z * k2.w + f.w * k3.w;
    }
    ((float4*)(h + (size_t)(row0 + r) * D))[cg] = acc;
}

// ---------------------------------------------------------------------------
// K2: bucket histogram via LDS privatization (391 bins fit in LDS)
// 1024 threads x 8 edges = 8192 edges/block, 196 blocks
// ---------------------------------------------------------------------------
__global__ __launch_bounds__(1024) void hist_kernel(
    const int* __restrict__ erow, u32* __restrict__ bcnt)
{
    __shared__ u32 c[NBUK];
    const int t = threadIdx.x;
    for (int i = t; i < NBUK; i += 1024) c[i] = 0u;
    __syncthreads();

    const int base = blockIdx.x * 8192;
    #pragma unroll
    for (int k = 0; k < 8; k++) {
        int i = base + k * 1024 + t;
        if (i < N_EDGES) atomicAdd(&c[erow[i] >> 8], 1u);
    }
    __syncthreads();
    for (int i = t; i < NBUK; i += 1024)
        if (c[i]) atomicAdd(&bcnt[i], c[i]);
}

// ---------------------------------------------------------------------------
// K3: exclusive scan of 391 bucket counts (single block), init cursors
// ---------------------------------------------------------------------------
__global__ void scan_kernel(const u32* __restrict__ bcnt,
                            u32* __restrict__ boff, u32* __restrict__ cur)
{
    __shared__ u32 s[512];
    const int t = threadIdx.x;
    u32 v = (t < NBUK) ? bcnt[t] : 0u;
    s[t] = v;
    __syncthreads();
    for (int d = 1; d < 512; d <<= 1) {
        u32 a = (t >= d) ? s[t - d] : 0u;
        __syncthreads();
        s[t] += a;
        __syncthreads();
    }
    if (t < NBUK) { u32 e = s[t] - v; boff[t] = e; cur[t] = e; }
}

// ---------------------------------------------------------------------------
// K4: place edges into bucket-grouped order.
// Per block: LDS count -> reserve contiguous range per bucket (1 global
// atomic per bucket per block) -> LDS rank -> dense packed 8B stores.
// Packs (col | row_local<<17, val) — col < 2^17, row_local < 256.
// ---------------------------------------------------------------------------
__global__ __launch_bounds__(1024) void place_kernel(
    const int* __restrict__ erow, const int* __restrict__ ecol,
    const float* __restrict__ eval, u32* __restrict__ cur,
    int2* __restrict__ sedge)
{
    __shared__ u32 c[NBUK];
    __shared__ u32 bl[NBUK];
    const int t = threadIdx.x;
    for (int i = t; i < NBUK; i += 1024) c[i] = 0u;
    __syncthreads();

    const int base = blockIdx.x * 8192;
    #pragma unroll
    for (int k = 0; k < 8; k++) {
        int i = base + k * 1024 + t;
        if (i < N_EDGES) atomicAdd(&c[erow[i] >> 8], 1u);
    }
    __syncthreads();
    for (int i = t; i < NBUK; i += 1024)
        bl[i] = atomicAdd(&cur[i], c[i]);
    __syncthreads();
    for (int i = t; i < NBUK; i += 1024) c[i] = 0u;
    __syncthreads();

    #pragma unroll
    for (int k = 0; k < 8; k++) {
        int i = base + k * 1024 + t;
        if (i < N_EDGES) {
            int r = erow[i];
            int b = r >> 8;
            u32 rk = atomicAdd(&c[b], 1u);
            sedge[bl[b] + rk] = make_int2(ecol[i] | ((r & 255) << 17),
                                          __float_as_int(eval[i]));
        }
    }
}

// ---------------------------------------------------------------------------
// K5: bucket aggregation. One block per bucket (256 rows), 64 KB LDS fp32
// accumulator. lane = dim; per edge: one coalesced 256B gather + one
// ds_add_f32 into rotated slot (lane+rl)&63 -> bank (lane+rl)&31, 2-way free.
// Fused skip/bias + SELU epilogue.
// ---------------------------------------------------------------------------
__global__ __launch_bounds__(1024) void agg_kernel(
    const u32* __restrict__ boff, const u32* __restrict__ bcnt,
    const int2* __restrict__ sedge, const float* __restrict__ h,
    const float* __restrict__ skip, const float* __restrict__ bias,
    float* __restrict__ out)
{
    __shared__ float acc[256 * 64];   // 64 KB

    const int t    = threadIdx.x;
    const int w    = t >> 6;          // wave 0..15
    const int lane = t & 63;
    const int b    = blockIdx.x;

    for (int i = t; i < 256 * 64; i += 1024) acc[i] = 0.f;
    __syncthreads();

    const u32 beg = boff[b];
    const u32 end = beg + bcnt[b];
    const float sk = skip[lane];
    const float bi = bias[lane];

    for (u32 j0 = beg + (u32)w * 8u; j0 < end; j0 += 128u) {
        #pragma unroll
        for (int i = 0; i < 8; i++) {
            u32 j = j0 + (u32)i;
            int2 e = (j < end) ? sedge[j] : make_int2(0, 0);
            u32 meta = (u32)e.x;
            int col = (int)(meta & 0x1FFFFu);
            int rl  = (int)(meta >> 17);
            float v  = __int_as_float(e.y);
            float hv = h[(size_t)col * D + lane];
            atomicAdd(&acc[rl * 64 + ((lane + rl) & 63)], v * hv);
        }
    }
    __syncthreads();

    const int rows = min(256, N_NODES - b * 256);
    const float scale = 1.0507009873554805f;
    const float alpha = 1.6732632423543772f;
    for (int r = w; r < rows; r += 16) {
        int grow = b * 256 + r;
        float x = h[(size_t)grow * D + lane] * sk + bi
                + acc[r * 64 + ((lane + r) & 63)];
        out[(size_t)grow * D + lane] =
            x > 0.f ? scale * x : scale * alpha * (expf(x) - 1.f);
    }
}

extern "C" void kernel_launch(void* const* d_in, const int* in_sizes, int n_in,
                              void* d_out, int out_size, void* d_ws, size_t ws_size,
                              hipStream_t stream)
{
    const float* feat = (const float*)d_in[0];
    const float* kern = (const float*)d_in[1];
    const float* bias = (const float*)d_in[2];
    const float* skip = (const float*)d_in[3];
    const int*   erow = (const int*)d_in[4];
    const int*   ecol = (const int*)d_in[5];
    const float* eval = (const float*)d_in[6];
    float* out = (float*)d_out;

    // workspace layout
    float* h     = (float*)d_ws;                       // 6,400,000 f (25.6 MB)
    u32*   bcnt  = (u32*)(h + (size_t)N_NODES * D);    // 512 (391 used)
    u32*   boff  = bcnt + 512;                         // 512
    u32*   cur   = boff + 512;                         // 512
    int2*  sedge = (int2*)(cur + 512);                 // 1,600,000 int2 (12.8 MB)
    // total ~38.4 MB

    hipLaunchKernelGGL(gemm_kernel, dim3(N_NODES / 16), dim3(256), 0, stream,
                       feat, kern, h, bcnt);
    hipLaunchKernelGGL(hist_kernel, dim3(196), dim3(1024), 0, stream,
                       erow, bcnt);
    hipLaunchKernelGGL(scan_kernel, dim3(1), dim3(512), 0, stream,
                       bcnt, boff, cur);
    hipLaunchKernelGGL(place_kernel, dim3(196), dim3(1024), 0, stream,
                       erow, ecol, eval, cur, sedge);
    hipLaunchKernelGGL(agg_kernel, dim3(NBUK), dim3(1024), 0, stream,
                       boff, bcnt, sedge, h, skip, bias, out);
}

// Round 6
// 206.240 us; speedup vs baseline: 4.0604x; 4.0604x over previous
//
#include <hip/hip_runtime.h>
#include <math.h>

#define N_NODES 100000
#define N_EDGES 1600000
#define D 64
#define RPB 128                  // rows per bucket
#define NBUK 782                 // ceil(N_NODES/128)
#define CAP 3072                 // LDS edge buffer per bucket (mean 2046, +16 sigma)

typedef unsigned int u32;

// ---------------------------------------------------------------------------
// K1: h = feat @ kern  (fp32 vector GEMM, K=64, D_OUT=64)
//     block 0 additionally zeroes the bucket counters.
// ---------------------------------------------------------------------------
__global__ __launch_bounds__(256) void gemm_kernel(
    const float* __restrict__ feat, const float* __restrict__ kern,
    float* __restrict__ h, u32* __restrict__ bcnt)
{
    __shared__ float ks[64 * 64];
    __shared__ float fs[16 * 64];

    const int t = threadIdx.x;
    const int row0 = blockIdx.x * 16;

    if (blockIdx.x == 0)
        for (int i = t; i < NBUK; i += 256) bcnt[i] = 0u;

    {
        const float4* k4 = (const float4*)kern;
        float4* ks4 = (float4*)ks;
        #pragma unroll
        for (int i = 0; i < 4; i++) ks4[t + 256 * i] = k4[t + 256 * i];
    }
    {
        const float4* f4 = (const float4*)(feat + (size_t)row0 * D);
        ((float4*)fs)[t] = f4[t];
    }
    __syncthreads();

    const int r  = t >> 4;
    const int cg = t & 15;

    float4 acc = make_float4(0.f, 0.f, 0.f, 0.f);
    #pragma unroll
    for (int k4 = 0; k4 < 16; k4++) {
        float4 f  = ((const float4*)(fs + r * D))[k4];
        float4 k0 = ((const float4*)(ks + (4 * k4 + 0) * D))[cg];
        float4 k1 = ((const float4*)(ks + (4 * k4 + 1) * D))[cg];
        float4 k2 = ((const float4*)(ks + (4 * k4 + 2) * D))[cg];
        float4 k3 = ((const float4*)(ks + (4 * k4 + 3) * D))[cg];
        acc.x += f.x * k0.x + f.y * k1.x + f.z * k2.x + f.w * k3.x;
        acc.y += f.x * k0.y + f.y * k1.y + f.z * k2.y + f.w * k3.y;
        acc.z += f.x * k0.z + f.y * k1.z + f.z * k2.z + f.w * k3.z;
        acc.w += f.x * k0.w + f.y * k1.w + f.z * k2.w + f.w * k3.w;
    }
    ((float4*)(h + (size_t)(row0 + r) * D))[cg] = acc;
}

// ---------------------------------------------------------------------------
// K2: bucket histogram, LDS-privatized (u32 LDS atomics are native ds_add)
// ---------------------------------------------------------------------------
__global__ __launch_bounds__(1024) void hist_kernel(
    const int* __restrict__ erow, u32* __restrict__ bcnt)
{
    __shared__ u32 c[NBUK];
    const int t = threadIdx.x;
    for (int i = t; i < NBUK; i += 1024) c[i] = 0u;
    __syncthreads();

    const int base = blockIdx.x * 8192;
    #pragma unroll
    for (int k = 0; k < 8; k++) {
        int i = base + k * 1024 + t;
        if (i < N_EDGES) atomicAdd(&c[erow[i] >> 7], 1u);
    }
    __syncthreads();
    for (int i = t; i < NBUK; i += 1024)
        if (c[i]) atomicAdd(&bcnt[i], c[i]);
}

// ---------------------------------------------------------------------------
// K3: exclusive scan of NBUK bucket counts (single 1024-thread block)
// ---------------------------------------------------------------------------
__global__ __launch_bounds__(1024) void scan_kernel(
    const u32* __restrict__ bcnt, u32* __restrict__ boff, u32* __restrict__ cur)
{
    __shared__ u32 s[1024];
    const int t = threadIdx.x;
    u32 v = (t < NBUK) ? bcnt[t] : 0u;
    s[t] = v;
    __syncthreads();
    for (int d = 1; d < 1024; d <<= 1) {
        u32 a = (t >= d) ? s[t - d] : 0u;
        __syncthreads();
        s[t] += a;
        __syncthreads();
    }
    if (t < NBUK) { u32 e = s[t] - v; boff[t] = e; cur[t] = e; }
}

// ---------------------------------------------------------------------------
// K4: place edges bucket-grouped. Per (block,bucket) a contiguous range is
// reserved (one global atomic per bucket per block), so stores are dense runs.
// Packs (col | row_local<<17, val): col < 2^17, row_local < 128.
// ---------------------------------------------------------------------------
__global__ __launch_bounds__(1024) void place_kernel(
    const int* __restrict__ erow, const int* __restrict__ ecol,
    const float* __restrict__ eval, u32* __restrict__ cur,
    int2* __restrict__ sedge)
{
    __shared__ u32 c[NBUK];
    __shared__ u32 bl[NBUK];
    const int t = threadIdx.x;
    for (int i = t; i < NBUK; i += 1024) c[i] = 0u;
    __syncthreads();

    const int base = blockIdx.x * 8192;
    #pragma unroll
    for (int k = 0; k < 8; k++) {
        int i = base + k * 1024 + t;
        if (i < N_EDGES) atomicAdd(&c[erow[i] >> 7], 1u);
    }
    __syncthreads();
    for (int i = t; i < NBUK; i += 1024)
        bl[i] = atomicAdd(&cur[i], c[i]);
    __syncthreads();
    for (int i = t; i < NBUK; i += 1024) c[i] = 0u;
    __syncthreads();

    #pragma unroll
    for (int k = 0; k < 8; k++) {
        int i = base + k * 1024 + t;
        if (i < N_EDGES) {
            int r = erow[i];
            int b = r >> 7;
            u32 rk = atomicAdd(&c[b], 1u);
            sedge[bl[b] + rk] = make_int2(ecol[i] | ((r & 127) << 17),
                                          __float_as_int(eval[i]));
        }
    }
}

// ---------------------------------------------------------------------------
// K5: aggregation. One block per 128-row bucket. In-LDS counting sort by
// local row (u32 LDS atomics + 128-wide scan), then R4-style wave-per-row
// gather: quarter-wave handles one edge, each lane loads float4 of h
// (1 KB per dwordx4 across the wave), shuffle reduce, fused skip/bias+SELU.
// No fp atomics anywhere.
// ---------------------------------------------------------------------------
__global__ __launch_bounds__(1024) void agg_kernel(
    const u32* __restrict__ boff, const u32* __restrict__ bcnt,
    const int2* __restrict__ sedge, const float* __restrict__ h,
    const float* __restrict__ skip, const float* __restrict__ bias,
    float* __restrict__ out)
{
    __shared__ int2 ebuf[CAP];        // 24 KB row-sorted edges
    __shared__ u32 c[RPB];            // per-row count
    __shared__ u32 o[RPB];            // per-row exclusive offset
    __shared__ u32 cur[RPB];          // per-row cursor

    const int t = threadIdx.x;
    const int w = t >> 6;
    const int lane = t & 63;
    const int b = blockIdx.x;

    const u32 beg = boff[b];
    const u32 cnt = bcnt[b];

    if (t < RPB) c[t] = 0u;
    __syncthreads();

    // pass 1: per-row histogram
    for (u32 j = (u32)t; j < cnt; j += 1024u)
        atomicAdd(&c[(u32)sedge[beg + j].x >> 17], 1u);
    __syncthreads();

    // 128-wide exclusive scan (Hillis-Steele on inclusive, then subtract)
    if (t < RPB) o[t] = c[t];
    __syncthreads();
    for (int d = 1; d < RPB; d <<= 1) {
        u32 a = 0u;
        if (t < RPB && t >= d) a = o[t - d];
        __syncthreads();
        if (t < RPB && t >= d) o[t] += a;
        __syncthreads();
    }
    if (t < RPB) { u32 e = o[t] - c[t]; o[t] = e; cur[t] = e; }
    __syncthreads();

    // pass 2: scatter into LDS row-sorted (sedge re-read is L2-hot)
    for (u32 j = (u32)t; j < cnt; j += 1024u) {
        int2 e = sedge[beg + j];
        u32 rl = (u32)e.x >> 17;
        u32 rk = atomicAdd(&cur[rl], 1u);
        if (rk < CAP) ebuf[rk] = make_int2(e.x & 0x1FFFF, e.y);
    }
    __syncthreads();

    // per-row gather + reduce
    const int rows = min(RPB, N_NODES - b * RPB);
    const int sub = lane >> 4;
    const int dg  = lane & 15;
    const float scale = 1.0507009873554805f;
    const float alpha = 1.6732632423543772f;

    for (int rl = w; rl < rows; rl += 16) {
        const u32 jb = o[rl];
        const u32 n  = c[rl];
        float4 acc = make_float4(0.f, 0.f, 0.f, 0.f);

        for (u32 j = 0; j < n; j += 8u) {
            u32 ja = j + (u32)sub;
            u32 jb2 = j + 4u + (u32)sub;
            int2 ea = (ja < n && jb + ja < CAP) ? ebuf[jb + ja] : make_int2(0, 0);
            int2 eb = (jb2 < n && jb + jb2 < CAP) ? ebuf[jb + jb2] : make_int2(0, 0);
            float va = __int_as_float(ea.y);
            float vb = __int_as_float(eb.y);
            float4 ha = ((const float4*)(h + (size_t)ea.x * D))[dg];
            float4 hb = ((const float4*)(h + (size_t)eb.x * D))[dg];
            acc.x += va * ha.x; acc.y += va * ha.y;
            acc.z += va * ha.z; acc.w += va * ha.w;
            acc.x += vb * hb.x; acc.y += vb * hb.y;
            acc.z += vb * hb.z; acc.w += vb * hb.w;
        }

        acc.x += __shfl_xor(acc.x, 16); acc.y += __shfl_xor(acc.y, 16);
        acc.z += __shfl_xor(acc.z, 16); acc.w += __shfl_xor(acc.w, 16);
        acc.x += __shfl_xor(acc.x, 32); acc.y += __shfl_xor(acc.y, 32);
        acc.z += __shfl_xor(acc.z, 32); acc.w += __shfl_xor(acc.w, 32);

        if (sub == 0) {
            const int grow = b * RPB + rl;
            float4 hr = ((const float4*)(h + (size_t)grow * D))[dg];
            float4 sk = ((const float4*)skip)[dg];
            float4 bi = ((const float4*)bias)[dg];
            float4 x;
            x.x = hr.x * sk.x + bi.x + acc.x;
            x.y = hr.y * sk.y + bi.y + acc.y;
            x.z = hr.z * sk.z + bi.z + acc.z;
            x.w = hr.w * sk.w + bi.w + acc.w;
            x.x = x.x > 0.f ? scale * x.x : scale * alpha * (expf(x.x) - 1.f);
            x.y = x.y > 0.f ? scale * x.y : scale * alpha * (expf(x.y) - 1.f);
            x.z = x.z > 0.f ? scale * x.z : scale * alpha * (expf(x.z) - 1.f);
            x.w = x.w > 0.f ? scale * x.w : scale * alpha * (expf(x.w) - 1.f);
            ((float4*)(out + (size_t)grow * D))[dg] = x;
        }
    }
}

extern "C" void kernel_launch(void* const* d_in, const int* in_sizes, int n_in,
                              void* d_out, int out_size, void* d_ws, size_t ws_size,
                              hipStream_t stream)
{
    const float* feat = (const float*)d_in[0];
    const float* kern = (const float*)d_in[1];
    const float* bias = (const float*)d_in[2];
    const float* skip = (const float*)d_in[3];
    const int*   erow = (const int*)d_in[4];
    const int*   ecol = (const int*)d_in[5];
    const float* eval = (const float*)d_in[6];
    float* out = (float*)d_out;

    // workspace layout
    float* h     = (float*)d_ws;                       // 6,400,000 f (25.6 MB)
    u32*   bcnt  = (u32*)(h + (size_t)N_NODES * D);    // 1024 (782 used)
    u32*   boff  = bcnt + 1024;                        // 1024
    u32*   cur   = boff + 1024;                        // 1024
    int2*  sedge = (int2*)(cur + 1024);                // 1,600,000 int2 (12.8 MB)
    // total ~38.4 MB

    hipLaunchKernelGGL(gemm_kernel, dim3(N_NODES / 16), dim3(256), 0, stream,
                       feat, kern, h, bcnt);
    hipLaunchKernelGGL(hist_kernel, dim3(196), dim3(1024), 0, stream,
                       erow, bcnt);
    hipLaunchKernelGGL(scan_kernel, dim3(1), dim3(1024), 0, stream,
                       bcnt, boff, cur);
    hipLaunchKernelGGL(place_kernel, dim3(196), dim3(1024), 0, stream,
                       erow, ecol, eval, cur, sedge);
    hipLaunchKernelGGL(agg_kernel, dim3(NBUK), dim3(1024), 0, stream,
                       boff, bcnt, sedge, h, skip, bias, out);
}